// Round 2
// baseline (339.794 us; speedup 1.0000x reference)
//
#include <hip/hip_runtime.h>
#include <hip/hip_bf16.h>
#include <math.h>

#define HEADS 3
#define HO 384
#define NGRAPH 64
#define F_IN 256
#define SLOPE 0.2f

typedef __attribute__((ext_vector_type(8))) short bf8;
typedef __attribute__((ext_vector_type(4))) float f4;

// ---- bf16 helpers ----
__device__ __forceinline__ unsigned short bfr(float f) {
    unsigned u = __float_as_uint(f);
    u += 0x7fffu + ((u >> 16) & 1u);
    return (unsigned short)(u >> 16);
}
__device__ __forceinline__ float bflo(unsigned u) { return __uint_as_float(u << 16); }
__device__ __forceinline__ float bfhi(unsigned u) { return __uint_as_float(u & 0xffff0000u); }
__device__ __forceinline__ float lrelu(float v) { return (v > 0.f) ? v : SLOPE * v; }

// ---- K0: fused misc pre-pass (block-range dispatch):
//   blocks [0, NBc)       : degree count + per-edge rank (atomic returns rank)
//   blocks [NBc, NBc+384) : W -> WbT bf16 transpose-convert
//   block  NBc+384        : per-graph start offsets (batch sorted)
__global__ __launch_bounds__(256) void misc_k(const int* __restrict__ ei,
                                              const float* __restrict__ W,
                                              const int* __restrict__ batch,
                                              int* __restrict__ count,
                                              int* __restrict__ rank,
                                              short* __restrict__ WbT,
                                              int* __restrict__ gstart,
                                              int NBc, int E, int N) {
    int b = blockIdx.x;
    if (b < NBc) {
        int e = b * 256 + threadIdx.x;
        int ET = E + N;
        if (e >= ET) return;
        int d = (e < E) ? ei[E + e] : (e - E);
        rank[e] = atomicAdd(&count[d], 1);   // unique within-dst rank
    } else if (b < NBc + 384) {
        int n = b - NBc;
        int k = threadIdx.x;
        WbT[n * 256 + k] = (short)bfr(W[(size_t)k * HO + n]);
    } else {
        int g = threadIdx.x;
        if (g > NGRAPH) return;
        int lo = 0, hi = N;
        while (lo < hi) { int mid = (lo + hi) >> 1; if (batch[mid] < g) lo = mid + 1; else hi = mid; }
        gstart[g] = lo;
    }
}

// ---- K1: LDS-staged bf16 MFMA GEMM + attention-dot epilogue (best measured:
// 256 thr, X+B staged in LDS, X register-prefetched one chunk ahead) ----
#define XS_STRIDE 40
__global__ __launch_bounds__(256, 3) void gemm_att(const float* __restrict__ X,
                                                   const short* __restrict__ WbT,
                                                   const float* __restrict__ att_src,
                                                   const float* __restrict__ att_dst,
                                                   unsigned* __restrict__ Hb,
                                                   float* __restrict__ aSrcO,
                                                   float* __restrict__ aDstO, int N) {
    __shared__ short Xs[64 * XS_STRIDE];
    __shared__ short Bs[384 * XS_STRIDE];
    __shared__ float lsS[64][8];
    __shared__ float lsD[64][8];
    int t = threadIdx.x;
    int w = t >> 6, lane = t & 63;
    int quad = lane >> 4, l15 = lane & 15;
    int rbase = blockIdx.x * 64;

    int sr = t >> 2;             // 0..63 (X row)
    int sko = (t & 3) * 8;       // 0,8,16,24
    int xrow = rbase + sr;
    xrow = (xrow < N) ? xrow : (N - 1);   // clamped rows never stored
    const float* xrp = X + (size_t)xrow * F_IN;

    f4 acc[4][6] = {};

    float4 p0 = *(const float4*)(xrp + sko);
    float4 p1 = *(const float4*)(xrp + sko + 4);

    for (int k0 = 0; k0 < F_IN; k0 += 32) {
        __syncthreads();
        {
            bf8 pk;
            pk[0] = (short)bfr(p0.x); pk[1] = (short)bfr(p0.y);
            pk[2] = (short)bfr(p0.z); pk[3] = (short)bfr(p0.w);
            pk[4] = (short)bfr(p1.x); pk[5] = (short)bfr(p1.y);
            pk[6] = (short)bfr(p1.z); pk[7] = (short)bfr(p1.w);
            *(bf8*)(&Xs[sr * XS_STRIDE + sko]) = pk;
        }
#pragma unroll
        for (int i = 0; i < 6; i++) {
            int n = i * 64 + sr;
            bf8 b = *(const bf8*)(WbT + (size_t)n * F_IN + k0 + sko);
            *(bf8*)(&Bs[n * XS_STRIDE + sko]) = b;
        }
        __syncthreads();
        if (k0 + 32 < F_IN) {    // prefetch next X chunk under the MFMAs
            p0 = *(const float4*)(xrp + k0 + 32 + sko);
            p1 = *(const float4*)(xrp + k0 + 32 + sko + 4);
        }
        bf8 ar[4], br[6];
#pragma unroll
        for (int at = 0; at < 4; at++)
            ar[at] = *(const bf8*)(&Xs[(at * 16 + l15) * XS_STRIDE + quad * 8]);
#pragma unroll
        for (int nt = 0; nt < 6; nt++)
            br[nt] = *(const bf8*)(&Bs[(w * 96 + nt * 16 + l15) * XS_STRIDE + quad * 8]);
#pragma unroll
        for (int at = 0; at < 4; at++)
#pragma unroll
            for (int nt = 0; nt < 6; nt++)
                acc[at][nt] = __builtin_amdgcn_mfma_f32_16x16x32_bf16(ar[at], br[nt], acc[at][nt], 0, 0, 0);
    }

    // ---- attention-dot epilogue ----
    // w=0: all head0 (split 6) | w=1: nt<2 head0, rest head1 (split 2)
    // w=2: nt<4 head1, rest head2 (split 4) | w=3: all head2 (split 0)
    const int splits[4] = {6, 2, 4, 0};
    int split = splits[w];
    float asv[6], adv[6];
#pragma unroll
    for (int nt = 0; nt < 6; nt++) {
        int c = w * 96 + nt * 16 + l15;
        asv[nt] = att_src[c];
        adv[nt] = att_dst[c];
    }
#pragma unroll
    for (int at = 0; at < 4; at++) {
#pragma unroll
        for (int r = 0; r < 4; r++) {
            float paS = 0.f, pbS = 0.f, paD = 0.f, pbD = 0.f;
#pragma unroll
            for (int nt = 0; nt < 6; nt++) {
                float v = acc[at][nt][r];
                if (nt < split) { paS += v * asv[nt]; paD += v * adv[nt]; }
                else            { pbS += v * asv[nt]; pbD += v * adv[nt]; }
            }
#pragma unroll
            for (int off = 1; off < 16; off <<= 1) {
                paS += __shfl_xor(paS, off); pbS += __shfl_xor(pbS, off);
                paD += __shfl_xor(paD, off); pbD += __shfl_xor(pbD, off);
            }
            if (l15 == 0) {
                int row = at * 16 + quad * 4 + r;
                lsS[row][w * 2 + 0] = paS; lsS[row][w * 2 + 1] = pbS;
                lsD[row][w * 2 + 0] = paD; lsD[row][w * 2 + 1] = pbD;
            }
        }
    }
    // ---- Hb store (C/D layout: col = lane&15, row = quad*4 + reg) ----
#pragma unroll
    for (int at = 0; at < 4; at++) {
#pragma unroll
        for (int nt = 0; nt < 6; nt++) {
#pragma unroll
            for (int r = 0; r < 4; r++) {
                float v = acc[at][nt][r];
                float vp = __shfl_xor(v, 1);
                int node = rbase + at * 16 + quad * 4 + r;
                if (!(lane & 1) && node < N) {
                    unsigned pk = (unsigned)bfr(v) | ((unsigned)bfr(vp) << 16);
                    Hb[(size_t)node * 192 + w * 48 + nt * 8 + (l15 >> 1)] = pk;
                }
            }
        }
    }
    __syncthreads();
    if (t < 64) {
        int node = rbase + t;
        if (node < N) {
            aSrcO[node * 3 + 0] = lsS[t][0] + lsS[t][2];
            aSrcO[node * 3 + 1] = lsS[t][3] + lsS[t][4];
            aSrcO[node * 3 + 2] = lsS[t][5] + lsS[t][7];
            aDstO[node * 3 + 0] = lsD[t][0] + lsD[t][2];
            aDstO[node * 3 + 1] = lsD[t][3] + lsD[t][4];
            aDstO[node * 3 + 2] = lsD[t][5] + lsD[t][7];
        }
    }
}

// ---- K2a/b/c: hierarchical exclusive scan ----
__global__ __launch_bounds__(256) void scan_a(const int* __restrict__ count,
                                              int* __restrict__ offsets,
                                              int* __restrict__ bsums, int N) {
    __shared__ int tmp[256];
    int t = threadIdx.x;
    int i = blockIdx.x * 256 + t;
    int v = (i < N) ? count[i] : 0;
    tmp[t] = v;
    __syncthreads();
    for (int off = 1; off < 256; off <<= 1) {
        int x = (t >= off) ? tmp[t - off] : 0;
        __syncthreads();
        tmp[t] += x;
        __syncthreads();
    }
    if (i < N) offsets[i] = tmp[t] - v;
    if (t == 255) bsums[blockIdx.x] = tmp[255];
}

__global__ __launch_bounds__(256) void scan_b(int* __restrict__ bsums, int NB) {
    __shared__ int tmp[256];
    int t = threadIdx.x;
    int v = (t < NB) ? bsums[t] : 0;
    tmp[t] = v;
    __syncthreads();
    for (int off = 1; off < 256; off <<= 1) {
        int x = (t >= off) ? tmp[t - off] : 0;
        __syncthreads();
        tmp[t] += x;
        __syncthreads();
    }
    if (t < NB) bsums[t] = tmp[t] - v;
}

__global__ __launch_bounds__(256) void scan_c(int* __restrict__ offsets,
                                              const int* __restrict__ bsums, int N) {
    int i = blockIdx.x * 256 + threadIdx.x;
    if (i < N) offsets[i] += bsums[blockIdx.x];
}

// ---- K3: scatter src index into CSR — plain write via precomputed rank ----
__global__ __launch_bounds__(256) void scatter_k(const int* __restrict__ ei,
                                                 const int* __restrict__ rank,
                                                 const int* __restrict__ offsets,
                                                 int* __restrict__ csr_src, int E, int N) {
    int e = blockIdx.x * 256 + threadIdx.x;
    int ET = E + N;
    if (e >= ET) return;
    int s, d;
    if (e < E) { s = ei[e]; d = ei[E + e]; } else { s = e - E; d = s; }
    csr_src[offsets[d] + rank[e]] = s;
}

// ---- K4: fused softmax + aggregation, one wave per dst ----
// Round-1: non-temporal outb stores (stop the 37.5 MB write stream from
// evicting Hb out of the 4 MB per-XCD L2 — gather hit rate is the lever),
// non-temporal once-read csr_src load.
__global__ __launch_bounds__(256) void aggregate_k(const unsigned* __restrict__ Hb,
                                                   const int* __restrict__ csr_src,
                                                   const int* __restrict__ offsets,
                                                   const int* __restrict__ count,
                                                   const float* __restrict__ a_src,
                                                   const float* __restrict__ a_dst,
                                                   const float* __restrict__ bias,
                                                   unsigned* __restrict__ outb, int N) {
    int wid = blockIdx.x * 4 + (threadIdx.x >> 6);
    int lane = threadIdx.x & 63;
    if (wid >= N) return;
    int start = offsets[wid], n = count[wid];
    float ad0 = a_dst[wid * 3 + 0], ad1 = a_dst[wid * 3 + 1], ad2 = a_dst[wid * 3 + 2];
    float a0l = 0.f, a0h = 0.f, a1l = 0.f, a1h = 0.f, a2l = 0.f, a2h = 0.f;

    if (n <= 64) {
        int sreg = 0;
        float l0 = -INFINITY, l1 = -INFINITY, l2 = -INFINITY;
        if (lane < n) {
            sreg = __builtin_nontemporal_load(csr_src + start + lane);
            l0 = lrelu(a_src[sreg * 3 + 0] + ad0);
            l1 = lrelu(a_src[sreg * 3 + 1] + ad1);
            l2 = lrelu(a_src[sreg * 3 + 2] + ad2);
        }
        // ---- issue batch 0 gather NOW; it completes under the softmax ----
        unsigned u0[8], u1[8], u2[8];
#pragma unroll
        for (int q = 0; q < 8; q++) {
            int s = __shfl(sreg, q);                 // lanes >= n: sreg=0 -> row 0 (valid)
            const unsigned* h = Hb + (size_t)s * 192;
            u0[q] = h[lane]; u1[q] = h[lane + 64]; u2[q] = h[lane + 128];
        }
        // ---- softmax reductions (overlapped with the loads above) ----
        float m0 = l0, m1 = l1, m2 = l2;
#pragma unroll
        for (int off = 1; off < 64; off <<= 1) {
            m0 = fmaxf(m0, __shfl_xor(m0, off));
            m1 = fmaxf(m1, __shfl_xor(m1, off));
            m2 = fmaxf(m2, __shfl_xor(m2, off));
        }
        float e0 = (lane < n) ? expf(l0 - m0) : 0.f;   // unnormalized weight; 0 beyond n
        float e1 = (lane < n) ? expf(l1 - m1) : 0.f;
        float e2 = (lane < n) ? expf(l2 - m2) : 0.f;
        float s0 = e0, s1 = e1, s2 = e2;
#pragma unroll
        for (int off = 1; off < 64; off <<= 1) {
            s0 += __shfl_xor(s0, off);
            s1 += __shfl_xor(s1, off);
            s2 += __shfl_xor(s2, off);
        }
        float i0 = 1.f / (s0 + 1e-16f), i1 = 1.f / (s1 + 1e-16f), i2 = 1.f / (s2 + 1e-16f);
        // ---- fully batched gather: partial batches are exact (w=0 lanes) ----
        for (int j = 0; j < n; j += 8) {
            float wq0[8], wq1[8], wq2[8];
#pragma unroll
            for (int q = 0; q < 8; q++) {            // j+q <= 63 always (j mult of 8, j < n <= 64)
                wq0[q] = __shfl(e0, j + q);
                wq1[q] = __shfl(e1, j + q);
                wq2[q] = __shfl(e2, j + q);
            }
#pragma unroll
            for (int q = 0; q < 8; q++) {
                a0l += wq0[q] * bflo(u0[q]); a0h += wq0[q] * bfhi(u0[q]);
                a1l += wq1[q] * bflo(u1[q]); a1h += wq1[q] * bfhi(u1[q]);
                a2l += wq2[q] * bflo(u2[q]); a2h += wq2[q] * bfhi(u2[q]);
            }
            if (j + 8 < n) {                          // wave-uniform; issue next batch
#pragma unroll
                for (int q = 0; q < 8; q++) {
                    int s = __shfl(sreg, j + 8 + q);
                    const unsigned* h = Hb + (size_t)s * 192;
                    u0[q] = h[lane]; u1[q] = h[lane + 64]; u2[q] = h[lane + 128];
                }
            }
        }
        // ---- deferred softmax normalization ----
        a0l *= i0; a0h *= i0;
        a1l *= i1; a1h *= i1;
        a2l *= i2; a2h *= i2;
    } else {
        float m0 = -INFINITY, m1 = -INFINITY, m2 = -INFINITY;
        for (int j = lane; j < n; j += 64) {
            int s = csr_src[start + j];
            m0 = fmaxf(m0, lrelu(a_src[s * 3 + 0] + ad0));
            m1 = fmaxf(m1, lrelu(a_src[s * 3 + 1] + ad1));
            m2 = fmaxf(m2, lrelu(a_src[s * 3 + 2] + ad2));
        }
#pragma unroll
        for (int off = 1; off < 64; off <<= 1) {
            m0 = fmaxf(m0, __shfl_xor(m0, off));
            m1 = fmaxf(m1, __shfl_xor(m1, off));
            m2 = fmaxf(m2, __shfl_xor(m2, off));
        }
        float s0 = 0.f, s1 = 0.f, s2 = 0.f;
        for (int j = lane; j < n; j += 64) {
            int s = csr_src[start + j];
            s0 += expf(lrelu(a_src[s * 3 + 0] + ad0) - m0);
            s1 += expf(lrelu(a_src[s * 3 + 1] + ad1) - m1);
            s2 += expf(lrelu(a_src[s * 3 + 2] + ad2) - m2);
        }
#pragma unroll
        for (int off = 1; off < 64; off <<= 1) {
            s0 += __shfl_xor(s0, off);
            s1 += __shfl_xor(s1, off);
            s2 += __shfl_xor(s2, off);
        }
        float i0 = 1.f / (s0 + 1e-16f), i1 = 1.f / (s1 + 1e-16f), i2 = 1.f / (s2 + 1e-16f);
        for (int j = 0; j < n; j++) {
            int s = csr_src[start + j];
            float w0 = expf(lrelu(a_src[s * 3 + 0] + ad0) - m0) * i0;
            float w1 = expf(lrelu(a_src[s * 3 + 1] + ad1) - m1) * i1;
            float w2 = expf(lrelu(a_src[s * 3 + 2] + ad2) - m2) * i2;
            const unsigned* h = Hb + (size_t)s * 192;
            unsigned u0 = h[lane], u1 = h[lane + 64], u2 = h[lane + 128];
            a0l += w0 * bflo(u0); a0h += w0 * bfhi(u0);
            a1l += w1 * bflo(u1); a1h += w1 * bfhi(u1);
            a2l += w2 * bflo(u2); a2h += w2 * bfhi(u2);
        }
    }

    unsigned* orow = outb + (size_t)wid * 192;
    int c0 = 2 * lane;
    float b0 = bias[c0], b1 = bias[c0 + 1];
    float b2 = bias[128 + c0], b3 = bias[128 + c0 + 1];
    float b4 = bias[256 + c0], b5 = bias[256 + c0 + 1];
    float v, x0, x1;
    unsigned pk;
    v = a0l + b0; x0 = (v > 0.f) ? v : 0.f;
    v = a0h + b1; x1 = (v > 0.f) ? v : 0.f;
    pk = (unsigned)bfr(x0) | ((unsigned)bfr(x1) << 16);
    __builtin_nontemporal_store(pk, orow + lane);
    v = a1l + b2; x0 = (v > 0.f) ? v : 0.f;
    v = a1h + b3; x1 = (v > 0.f) ? v : 0.f;
    pk = (unsigned)bfr(x0) | ((unsigned)bfr(x1) << 16);
    __builtin_nontemporal_store(pk, orow + 64 + lane);
    v = a2l + b4; x0 = (v > 0.f) ? v : 0.f;
    v = a2h + b5; x1 = (v > 0.f) ? v : 0.f;
    pk = (unsigned)bfr(x0) | ((unsigned)bfr(x1) << 16);
    __builtin_nontemporal_store(pk, orow + 128 + lane);
}

// ---- K5: segment-sum pool over contiguous per-graph row ranges ----
__global__ __launch_bounds__(192) void pool_k(const unsigned* __restrict__ outb,
                                              const int* __restrict__ gstart,
                                              float* __restrict__ pooled) {
    int g = blockIdx.x;
    int chunk = blockIdx.y;
    int t = threadIdx.x;
    int lo = gstart[g], hi = gstart[g + 1];
    float al = 0.f, ah = 0.f;
    for (int r = lo + chunk; r < hi; r += 8) {
        unsigned u = __builtin_nontemporal_load(outb + (size_t)r * 192 + t);
        al += bflo(u);
        ah += bfhi(u);
    }
    atomicAdd(&pooled[g * HO + 2 * t], al);
    atomicAdd(&pooled[g * HO + 2 * t + 1], ah);
}

// ---- K6: FC over pooled means ----
__global__ __launch_bounds__(64) void fc_k(const float* __restrict__ pooled,
                                           const int* __restrict__ gstart,
                                           const float* __restrict__ fc_w,
                                           const float* __restrict__ fc_b,
                                           float* __restrict__ out) {
    int g = blockIdx.x;
    int lane = threadIdx.x;
    float a0 = 0.f, a1 = 0.f;
#pragma unroll
    for (int k = 0; k < 6; k++) {
        int c = lane + 64 * k;
        float pv = pooled[g * HO + c];
        a0 += pv * fc_w[c * 2 + 0];
        a1 += pv * fc_w[c * 2 + 1];
    }
#pragma unroll
    for (int off = 32; off > 0; off >>= 1) {
        a0 += __shfl_down(a0, off);
        a1 += __shfl_down(a1, off);
    }
    if (lane == 0) {
        float cnt = fmaxf((float)(gstart[g + 1] - gstart[g]), 1.0f);
        out[g * 2 + 0] = a0 / cnt + fc_b[0];
        out[g * 2 + 1] = a1 / cnt + fc_b[1];
    }
}

extern "C" void kernel_launch(void* const* d_in, const int* in_sizes, int n_in,
                              void* d_out, int out_size, void* d_ws, size_t ws_size,
                              hipStream_t stream) {
    const float* x       = (const float*)d_in[0];
    const int*   ei      = (const int*)d_in[1];
    const int*   batch   = (const int*)d_in[2];
    const float* W       = (const float*)d_in[3];
    const float* att_src = (const float*)d_in[4];
    const float* att_dst = (const float*)d_in[5];
    const float* bias    = (const float*)d_in[6];
    const float* fc_w    = (const float*)d_in[7];
    const float* fc_b    = (const float*)d_in[8];
    float* out = (float*)d_out;

    const int N = in_sizes[2];
    const int E = in_sizes[1] / 2;
    const int ET = E + N;

    char* p = (char*)d_ws;
    auto alloc = [&](size_t bytes) -> char* {
        char* r = p;
        p += (bytes + 255) & ~(size_t)255;
        return r;
    };
    short*    wbt    = (short*)alloc((size_t)HO * F_IN * 2);
    unsigned* hb     = (unsigned*)alloc((size_t)N * 192 * 4);
    unsigned* outb   = (unsigned*)alloc((size_t)N * 192 * 4);
    float*    a_src  = (float*)alloc((size_t)N * 3 * 4);
    float*    a_dst  = (float*)alloc((size_t)N * 3 * 4);
    char*     zstart = p;
    int*      count  = (int*)alloc((size_t)N * 4);              // zeroed
    float*    pooled = (float*)alloc((size_t)NGRAPH * HO * 4);  // zeroed
    size_t    zbytes = (size_t)(p - zstart);
    int*      offsets = (int*)alloc((size_t)N * 4);
    int*      rank    = (int*)alloc((size_t)ET * 4);
    int*      bsums   = (int*)alloc(4096);
    int*      gstart  = (int*)alloc(1024);
    int*      csr_src = (int*)alloc((size_t)ET * 4);

    hipMemsetAsync(zstart, 0, zbytes, stream);

    int NBc = (ET + 255) / 256;
    misc_k<<<NBc + 384 + 1, 256, 0, stream>>>(ei, W, batch, count, rank, wbt, gstart,
                                              NBc, E, N);
    gemm_att<<<(N + 63) / 64, 256, 0, stream>>>(x, wbt, att_src, att_dst,
                                                hb, a_src, a_dst, N);
    int NB = (N + 255) / 256;
    scan_a<<<NB, 256, 0, stream>>>(count, offsets, bsums, N);
    scan_b<<<1, 256, 0, stream>>>(bsums, NB);
    scan_c<<<NB, 256, 0, stream>>>(offsets, bsums, N);
    scatter_k<<<(ET + 255) / 256, 256, 0, stream>>>(ei, rank, offsets, csr_src, E, N);
    aggregate_k<<<(N + 3) / 4, 256, 0, stream>>>(hb, csr_src, offsets, count,
                                                 a_src, a_dst, bias, outb, N);
    dim3 pg(NGRAPH, 8);
    pool_k<<<pg, 192, 0, stream>>>(outb, gstart, pooled);
    fc_k<<<NGRAPH, 64, 0, stream>>>(pooled, gstart, fc_w, fc_b, out);

    (void)n_in; (void)out_size; (void)ws_size;
}

// Round 3
// 312.669 us; speedup vs baseline: 1.0868x; 1.0868x over previous
//
#include <hip/hip_runtime.h>
#include <hip/hip_bf16.h>
#include <math.h>

#define HEADS 3
#define HO 384
#define NGRAPH 64
#define F_IN 256
#define SLOPE 0.2f

typedef __attribute__((ext_vector_type(8))) short bf8;
typedef __attribute__((ext_vector_type(4))) float f4;
typedef __attribute__((ext_vector_type(2))) unsigned u2v;
typedef __attribute__((ext_vector_type(4))) unsigned u4v;

// ---- bf16 helpers ----
__device__ __forceinline__ unsigned short bfr(float f) {
    unsigned u = __float_as_uint(f);
    u += 0x7fffu + ((u >> 16) & 1u);
    return (unsigned short)(u >> 16);
}
__device__ __forceinline__ float bflo(unsigned u) { return __uint_as_float(u << 16); }
__device__ __forceinline__ float bfhi(unsigned u) { return __uint_as_float(u & 0xffff0000u); }
__device__ __forceinline__ float lrelu(float v) { return (v > 0.f) ? v : SLOPE * v; }

// int8 row decode: 8 consecutive channels from 2 dwords, weighted FMA
__device__ __forceinline__ void dec_fma(float* acc, float wm, unsigned ux, unsigned uy) {
    acc[0] += wm * (float)((signed char)(ux));
    acc[1] += wm * (float)((signed char)(ux >> 8));
    acc[2] += wm * (float)((signed char)(ux >> 16));
    acc[3] += wm * (float)((signed char)(ux >> 24));
    acc[4] += wm * (float)((signed char)(uy));
    acc[5] += wm * (float)((signed char)(uy >> 8));
    acc[6] += wm * (float)((signed char)(uy >> 16));
    acc[7] += wm * (float)((signed char)(uy >> 24));
}

// ---- K0: fused misc pre-pass (block-range dispatch) ----
__global__ __launch_bounds__(256) void misc_k(const int* __restrict__ ei,
                                              const float* __restrict__ W,
                                              const int* __restrict__ batch,
                                              int* __restrict__ count,
                                              int* __restrict__ rank,
                                              short* __restrict__ WbT,
                                              int* __restrict__ gstart,
                                              int NBc, int E, int N) {
    int b = blockIdx.x;
    if (b < NBc) {
        int e = b * 256 + threadIdx.x;
        int ET = E + N;
        if (e >= ET) return;
        int d = (e < E) ? ei[E + e] : (e - E);
        rank[e] = atomicAdd(&count[d], 1);   // unique within-dst rank
    } else if (b < NBc + 384) {
        int n = b - NBc;
        int k = threadIdx.x;
        WbT[n * 256 + k] = (short)bfr(W[(size_t)k * HO + n]);
    } else {
        int g = threadIdx.x;
        if (g > NGRAPH) return;
        int lo = 0, hi = N;
        while (lo < hi) { int mid = (lo + hi) >> 1; if (batch[mid] < g) lo = mid + 1; else hi = mid; }
        gstart[g] = lo;
    }
}

// ---- K1: LDS-staged bf16 MFMA GEMM + attention-dot + int8-quant epilogue ----
// Outputs: Hc (N x 384 int8, per-(node,head) max-scaled), ni (N x 8 f32:
// [aSrc0,aSrc1,aSrc2,scale0][scale1,scale2,0,0]), aDstO (N x 3 f32).
#define XS_STRIDE 40
__global__ __launch_bounds__(256, 3) void gemm_att(const float* __restrict__ X,
                                                   const short* __restrict__ WbT,
                                                   const float* __restrict__ att_src,
                                                   const float* __restrict__ att_dst,
                                                   signed char* __restrict__ hc,
                                                   float* __restrict__ ni,
                                                   float* __restrict__ aDstO, int N) {
    __shared__ short Xs[64 * XS_STRIDE];
    __shared__ short Bs[384 * XS_STRIDE];
    __shared__ float lsS[64][8];
    __shared__ float lsD[64][8];
    __shared__ float lsM[64][8];
    __shared__ float sclS[64][4];
    int t = threadIdx.x;
    int w = t >> 6, lane = t & 63;
    int quad = lane >> 4, l15 = lane & 15;
    int rbase = blockIdx.x * 64;

    int sr = t >> 2;             // 0..63 (X row)
    int sko = (t & 3) * 8;       // 0,8,16,24
    int xrow = rbase + sr;
    xrow = (xrow < N) ? xrow : (N - 1);   // clamped rows never stored
    const float* xrp = X + (size_t)xrow * F_IN;

    f4 acc[4][6] = {};

    float4 p0 = *(const float4*)(xrp + sko);
    float4 p1 = *(const float4*)(xrp + sko + 4);

    for (int k0 = 0; k0 < F_IN; k0 += 32) {
        __syncthreads();
        {
            bf8 pk;
            pk[0] = (short)bfr(p0.x); pk[1] = (short)bfr(p0.y);
            pk[2] = (short)bfr(p0.z); pk[3] = (short)bfr(p0.w);
            pk[4] = (short)bfr(p1.x); pk[5] = (short)bfr(p1.y);
            pk[6] = (short)bfr(p1.z); pk[7] = (short)bfr(p1.w);
            *(bf8*)(&Xs[sr * XS_STRIDE + sko]) = pk;
        }
#pragma unroll
        for (int i = 0; i < 6; i++) {
            int n = i * 64 + sr;
            bf8 b = *(const bf8*)(WbT + (size_t)n * F_IN + k0 + sko);
            *(bf8*)(&Bs[n * XS_STRIDE + sko]) = b;
        }
        __syncthreads();
        if (k0 + 32 < F_IN) {    // prefetch next X chunk under the MFMAs
            p0 = *(const float4*)(xrp + k0 + 32 + sko);
            p1 = *(const float4*)(xrp + k0 + 32 + sko + 4);
        }
        bf8 ar[4], br[6];
#pragma unroll
        for (int at = 0; at < 4; at++)
            ar[at] = *(const bf8*)(&Xs[(at * 16 + l15) * XS_STRIDE + quad * 8]);
#pragma unroll
        for (int nt = 0; nt < 6; nt++)
            br[nt] = *(const bf8*)(&Bs[(w * 96 + nt * 16 + l15) * XS_STRIDE + quad * 8]);
#pragma unroll
        for (int at = 0; at < 4; at++)
#pragma unroll
            for (int nt = 0; nt < 6; nt++)
                acc[at][nt] = __builtin_amdgcn_mfma_f32_16x16x32_bf16(ar[at], br[nt], acc[at][nt], 0, 0, 0);
    }

    // ---- attention-dot epilogue ----
    // w=0: all head0 (split 6) | w=1: nt<2 head0, rest head1 (split 2)
    // w=2: nt<4 head1, rest head2 (split 4) | w=3: all head2 (split 0)
    const int splits[4] = {6, 2, 4, 0};
    int split = splits[w];
    float asv[6], adv[6];
#pragma unroll
    for (int nt = 0; nt < 6; nt++) {
        int c = w * 96 + nt * 16 + l15;
        asv[nt] = att_src[c];
        adv[nt] = att_dst[c];
    }
#pragma unroll
    for (int at = 0; at < 4; at++) {
#pragma unroll
        for (int r = 0; r < 4; r++) {
            float paS = 0.f, pbS = 0.f, paD = 0.f, pbD = 0.f;
#pragma unroll
            for (int nt = 0; nt < 6; nt++) {
                float v = acc[at][nt][r];
                if (nt < split) { paS += v * asv[nt]; paD += v * adv[nt]; }
                else            { pbS += v * asv[nt]; pbD += v * adv[nt]; }
            }
#pragma unroll
            for (int off = 1; off < 16; off <<= 1) {
                paS += __shfl_xor(paS, off); pbS += __shfl_xor(pbS, off);
                paD += __shfl_xor(paD, off); pbD += __shfl_xor(pbD, off);
            }
            if (l15 == 0) {
                int row = at * 16 + quad * 4 + r;
                lsS[row][w * 2 + 0] = paS; lsS[row][w * 2 + 1] = pbS;
                lsD[row][w * 2 + 0] = paD; lsD[row][w * 2 + 1] = pbD;
            }
        }
    }
    // ---- per-head abs-max (same split/reduce structure, fmax instead of +) ----
#pragma unroll
    for (int at = 0; at < 4; at++) {
#pragma unroll
        for (int r = 0; r < 4; r++) {
            float pa = 0.f, pb = 0.f;
#pragma unroll
            for (int nt = 0; nt < 6; nt++) {
                float v = fabsf(acc[at][nt][r]);
                if (nt < split) pa = fmaxf(pa, v); else pb = fmaxf(pb, v);
            }
#pragma unroll
            for (int off = 1; off < 16; off <<= 1) {
                pa = fmaxf(pa, __shfl_xor(pa, off));
                pb = fmaxf(pb, __shfl_xor(pb, off));
            }
            if (l15 == 0) {
                int row = at * 16 + quad * 4 + r;
                lsM[row][w * 2 + 0] = pa; lsM[row][w * 2 + 1] = pb;
            }
        }
    }
    __syncthreads();
    if (t < 64) {
        // per-head max over the two contributing waves (same combine as aSrc)
        float s0 = fmaxf(lsM[t][0], lsM[t][2]);
        float s1 = fmaxf(lsM[t][3], lsM[t][4]);
        float s2 = fmaxf(lsM[t][5], lsM[t][7]);
        sclS[t][0] = (s0 > 0.f) ? 127.f / s0 : 0.f;
        sclS[t][1] = (s1 > 0.f) ? 127.f / s1 : 0.f;
        sclS[t][2] = (s2 > 0.f) ? 127.f / s2 : 0.f;
        int node = rbase + t;
        if (node < N) {
            aDstO[node * 3 + 0] = lsD[t][0] + lsD[t][2];
            aDstO[node * 3 + 1] = lsD[t][3] + lsD[t][4];
            aDstO[node * 3 + 2] = lsD[t][5] + lsD[t][7];
            float4 nA, nB;
            nA.x = lsS[t][0] + lsS[t][2];
            nA.y = lsS[t][3] + lsS[t][4];
            nA.z = lsS[t][5] + lsS[t][7];
            nA.w = s0 / 127.f;            // pre-divided decode scale
            nB.x = s1 / 127.f;
            nB.y = s2 / 127.f;
            nB.z = 0.f; nB.w = 0.f;
            *(float4*)(ni + (size_t)node * 8) = nA;
            *(float4*)(ni + (size_t)node * 8 + 4) = nB;
        }
    }
    __syncthreads();
    // ---- int8 quantize + byte store: hc[node*384 + ch] ----
#pragma unroll
    for (int at = 0; at < 4; at++) {
#pragma unroll
        for (int nt = 0; nt < 6; nt++) {
            int hd = (w * 96 + nt * 16) >> 7;   // head of this 16-ch tile
#pragma unroll
            for (int r = 0; r < 4; r++) {
                int row = at * 16 + quad * 4 + r;
                int node = rbase + row;
                float rq = sclS[row][hd];
                int qi = (int)rintf(acc[at][nt][r] * rq);
                if (node < N) hc[(size_t)node * 384 + w * 96 + nt * 16 + l15] = (signed char)qi;
            }
        }
    }
}

// ---- K2a/b/c: hierarchical exclusive scan ----
__global__ __launch_bounds__(256) void scan_a(const int* __restrict__ count,
                                              int* __restrict__ offsets,
                                              int* __restrict__ bsums, int N) {
    __shared__ int tmp[256];
    int t = threadIdx.x;
    int i = blockIdx.x * 256 + t;
    int v = (i < N) ? count[i] : 0;
    tmp[t] = v;
    __syncthreads();
    for (int off = 1; off < 256; off <<= 1) {
        int x = (t >= off) ? tmp[t - off] : 0;
        __syncthreads();
        tmp[t] += x;
        __syncthreads();
    }
    if (i < N) offsets[i] = tmp[t] - v;
    if (t == 255) bsums[blockIdx.x] = tmp[255];
}

__global__ __launch_bounds__(256) void scan_b(int* __restrict__ bsums, int NB) {
    __shared__ int tmp[256];
    int t = threadIdx.x;
    int v = (t < NB) ? bsums[t] : 0;
    tmp[t] = v;
    __syncthreads();
    for (int off = 1; off < 256; off <<= 1) {
        int x = (t >= off) ? tmp[t - off] : 0;
        __syncthreads();
        tmp[t] += x;
        __syncthreads();
    }
    if (t < NB) bsums[t] = tmp[t] - v;
}

__global__ __launch_bounds__(256) void scan_c(int* __restrict__ offsets,
                                              const int* __restrict__ bsums, int N) {
    int i = blockIdx.x * 256 + threadIdx.x;
    if (i < N) offsets[i] += bsums[blockIdx.x];
}

// ---- K3: scatter src index into CSR — plain write via precomputed rank ----
__global__ __launch_bounds__(256) void scatter_k(const int* __restrict__ ei,
                                                 const int* __restrict__ rank,
                                                 const int* __restrict__ offsets,
                                                 int* __restrict__ csr_src, int E, int N) {
    int e = blockIdx.x * 256 + threadIdx.x;
    int ET = E + N;
    if (e >= ET) return;
    int s, d;
    if (e < E) { s = ei[e]; d = ei[E + e]; } else { s = e - E; d = s; }
    csr_src[offsets[d] + rank[e]] = s;
}

// ---- K4: fused softmax + int8-gather aggregation, one wave per dst ----
// Lane L < 48 owns channels [8L, 8L+8); head(L) = L>>4. Per edge: one
// dwordx2 gather (384 B/row total vs 768 bf16 — halves the per-XCD
// beyond-L2 fetch that is the measured ceiling). Scales folded into
// unnormalized softmax weights; i/127 folded into the final scale.
__global__ __launch_bounds__(256) void aggregate_k(const unsigned* __restrict__ hcw,
                                                   const int* __restrict__ csr_src,
                                                   const int* __restrict__ offsets,
                                                   const int* __restrict__ count,
                                                   const float* __restrict__ ni,
                                                   const float* __restrict__ a_dst,
                                                   const float* __restrict__ bias,
                                                   unsigned* __restrict__ outb, int N) {
    int wid = blockIdx.x * 4 + (threadIdx.x >> 6);
    int lane = threadIdx.x & 63;
    if (wid >= N) return;
    int start = offsets[wid], n = count[wid];
    float ad0 = a_dst[wid * 3 + 0], ad1 = a_dst[wid * 3 + 1], ad2 = a_dst[wid * 3 + 2];
    int head_my = lane >> 4;              // 0..2 for data lanes (<48)
    int off = (lane < 48) ? 2 * lane : 0; // dword offset into 96-dword row
    float acc[8] = {0.f, 0.f, 0.f, 0.f, 0.f, 0.f, 0.f, 0.f};
    float i0, i1, i2;

    if (n <= 64) {
        int sreg = 0;
        float l0 = -INFINITY, l1 = -INFINITY, l2 = -INFINITY;
        float s0v = 0.f, s1v = 0.f, s2v = 0.f;
        if (lane < n) {
            sreg = csr_src[start + lane];
            float4 A = *(const float4*)(ni + (size_t)sreg * 8);
            float4 B = *(const float4*)(ni + (size_t)sreg * 8 + 4);
            l0 = lrelu(A.x + ad0); l1 = lrelu(A.y + ad1); l2 = lrelu(A.z + ad2);
            s0v = A.w; s1v = B.x; s2v = B.y;
        }
        float m0 = l0, m1 = l1, m2 = l2;
#pragma unroll
        for (int o = 1; o < 64; o <<= 1) {
            m0 = fmaxf(m0, __shfl_xor(m0, o));
            m1 = fmaxf(m1, __shfl_xor(m1, o));
            m2 = fmaxf(m2, __shfl_xor(m2, o));
        }
        float e0 = (lane < n) ? expf(l0 - m0) : 0.f;
        float e1 = (lane < n) ? expf(l1 - m1) : 0.f;
        float e2 = (lane < n) ? expf(l2 - m2) : 0.f;
        float s0 = e0, s1 = e1, s2 = e2;
#pragma unroll
        for (int o = 1; o < 64; o <<= 1) {
            s0 += __shfl_xor(s0, o);
            s1 += __shfl_xor(s1, o);
            s2 += __shfl_xor(s2, o);
        }
        i0 = 1.f / (s0 + 1e-16f); i1 = 1.f / (s1 + 1e-16f); i2 = 1.f / (s2 + 1e-16f);
        // fold decode scale into unnormalized weights (zero for idle lanes)
        float f0 = e0 * s0v, f1 = e1 * s1v, f2 = e2 * s2v;

        for (int j = 0; j < n; j += 8) {
            unsigned ux[8], uy[8];
#pragma unroll
            for (int q = 0; q < 8; q++) {
                int s = __shfl(sreg, j + q);   // lanes >= n: sreg=0 -> row 0 (valid)
                u2v u = *(const u2v*)(hcw + (size_t)s * 96 + off);
                ux[q] = u.x; uy[q] = u.y;
            }
#pragma unroll
            for (int q = 0; q < 8; q++) {
                float w0 = __shfl(f0, j + q);
                float w1 = __shfl(f1, j + q);
                float w2 = __shfl(f2, j + q);
                float wm = (head_my == 0) ? w0 : ((head_my == 1) ? w1 : w2);
                dec_fma(acc, wm, ux[q], uy[q]);
            }
        }
    } else {
        float m0 = -INFINITY, m1 = -INFINITY, m2 = -INFINITY;
        for (int j = lane; j < n; j += 64) {
            int s = csr_src[start + j];
            float4 A = *(const float4*)(ni + (size_t)s * 8);
            m0 = fmaxf(m0, lrelu(A.x + ad0));
            m1 = fmaxf(m1, lrelu(A.y + ad1));
            m2 = fmaxf(m2, lrelu(A.z + ad2));
        }
#pragma unroll
        for (int o = 1; o < 64; o <<= 1) {
            m0 = fmaxf(m0, __shfl_xor(m0, o));
            m1 = fmaxf(m1, __shfl_xor(m1, o));
            m2 = fmaxf(m2, __shfl_xor(m2, o));
        }
        float s0 = 0.f, s1 = 0.f, s2 = 0.f;
        for (int j = lane; j < n; j += 64) {
            int s = csr_src[start + j];
            float4 A = *(const float4*)(ni + (size_t)s * 8);
            s0 += expf(lrelu(A.x + ad0) - m0);
            s1 += expf(lrelu(A.y + ad1) - m1);
            s2 += expf(lrelu(A.z + ad2) - m2);
        }
#pragma unroll
        for (int o = 1; o < 64; o <<= 1) {
            s0 += __shfl_xor(s0, o);
            s1 += __shfl_xor(s1, o);
            s2 += __shfl_xor(s2, o);
        }
        i0 = 1.f / (s0 + 1e-16f); i1 = 1.f / (s1 + 1e-16f); i2 = 1.f / (s2 + 1e-16f);
        for (int j = 0; j < n; j++) {
            int s = csr_src[start + j];
            float4 A = *(const float4*)(ni + (size_t)s * 8);
            float4 B = *(const float4*)(ni + (size_t)s * 8 + 4);
            float w0 = expf(lrelu(A.x + ad0) - m0) * A.w;
            float w1 = expf(lrelu(A.y + ad1) - m1) * B.x;
            float w2 = expf(lrelu(A.z + ad2) - m2) * B.y;
            float wm = (head_my == 0) ? w0 : ((head_my == 1) ? w1 : w2);
            u2v u = *(const u2v*)(hcw + (size_t)s * 96 + off);
            dec_fma(acc, wm, u.x, u.y);
        }
    }

    if (lane < 48) {
        float im = ((head_my == 0) ? i0 : (head_my == 1) ? i1 : i2);
        float4 b0 = *(const float4*)(bias + 8 * lane);
        float4 b1 = *(const float4*)(bias + 8 * lane + 4);
        float bb[8] = {b0.x, b0.y, b0.z, b0.w, b1.x, b1.y, b1.z, b1.w};
        u4v pk;
#pragma unroll
        for (int j = 0; j < 4; j++) {
            float x0 = acc[2 * j] * im + bb[2 * j];
            float x1 = acc[2 * j + 1] * im + bb[2 * j + 1];
            x0 = (x0 > 0.f) ? x0 : 0.f;
            x1 = (x1 > 0.f) ? x1 : 0.f;
            pk[j] = (unsigned)bfr(x0) | ((unsigned)bfr(x1) << 16);
        }
        *(u4v*)(outb + (size_t)wid * 192 + 4 * lane) = pk;
    }
}

// ---- K5: segment-sum pool over contiguous per-graph row ranges ----
__global__ __launch_bounds__(192) void pool_k(const unsigned* __restrict__ outb,
                                              const int* __restrict__ gstart,
                                              float* __restrict__ pooled) {
    int g = blockIdx.x;
    int chunk = blockIdx.y;
    int t = threadIdx.x;
    int lo = gstart[g], hi = gstart[g + 1];
    float al = 0.f, ah = 0.f;
    for (int r = lo + chunk; r < hi; r += 8) {
        unsigned u = outb[(size_t)r * 192 + t];
        al += bflo(u);
        ah += bfhi(u);
    }
    atomicAdd(&pooled[g * HO + 2 * t], al);
    atomicAdd(&pooled[g * HO + 2 * t + 1], ah);
}

// ---- K6: FC over pooled means ----
__global__ __launch_bounds__(64) void fc_k(const float* __restrict__ pooled,
                                           const int* __restrict__ gstart,
                                           const float* __restrict__ fc_w,
                                           const float* __restrict__ fc_b,
                                           float* __restrict__ out) {
    int g = blockIdx.x;
    int lane = threadIdx.x;
    float a0 = 0.f, a1 = 0.f;
#pragma unroll
    for (int k = 0; k < 6; k++) {
        int c = lane + 64 * k;
        float pv = pooled[g * HO + c];
        a0 += pv * fc_w[c * 2 + 0];
        a1 += pv * fc_w[c * 2 + 1];
    }
#pragma unroll
    for (int off = 32; off > 0; off >>= 1) {
        a0 += __shfl_down(a0, off);
        a1 += __shfl_down(a1, off);
    }
    if (lane == 0) {
        float cnt = fmaxf((float)(gstart[g + 1] - gstart[g]), 1.0f);
        out[g * 2 + 0] = a0 / cnt + fc_b[0];
        out[g * 2 + 1] = a1 / cnt + fc_b[1];
    }
}

extern "C" void kernel_launch(void* const* d_in, const int* in_sizes, int n_in,
                              void* d_out, int out_size, void* d_ws, size_t ws_size,
                              hipStream_t stream) {
    const float* x       = (const float*)d_in[0];
    const int*   ei      = (const int*)d_in[1];
    const int*   batch   = (const int*)d_in[2];
    const float* W       = (const float*)d_in[3];
    const float* att_src = (const float*)d_in[4];
    const float* att_dst = (const float*)d_in[5];
    const float* bias    = (const float*)d_in[6];
    const float* fc_w    = (const float*)d_in[7];
    const float* fc_b    = (const float*)d_in[8];
    float* out = (float*)d_out;

    const int N = in_sizes[2];
    const int E = in_sizes[1] / 2;
    const int ET = E + N;

    char* p = (char*)d_ws;
    auto alloc = [&](size_t bytes) -> char* {
        char* r = p;
        p += (bytes + 255) & ~(size_t)255;
        return r;
    };
    short*       wbt    = (short*)alloc((size_t)HO * F_IN * 2);
    signed char* hc     = (signed char*)alloc((size_t)N * 384);
    unsigned*    outb   = (unsigned*)alloc((size_t)N * 192 * 4);
    float*       ni     = (float*)alloc((size_t)N * 8 * 4);
    float*       a_dst  = (float*)alloc((size_t)N * 3 * 4);
    char*        zstart = p;
    int*         count  = (int*)alloc((size_t)N * 4);              // zeroed
    float*       pooled = (float*)alloc((size_t)NGRAPH * HO * 4);  // zeroed
    size_t       zbytes = (size_t)(p - zstart);
    int*         offsets = (int*)alloc((size_t)N * 4);
    int*         rank    = (int*)alloc((size_t)ET * 4);
    int*         bsums   = (int*)alloc(4096);
    int*         gstart  = (int*)alloc(1024);
    int*         csr_src = (int*)alloc((size_t)ET * 4);

    hipMemsetAsync(zstart, 0, zbytes, stream);

    int NBc = (ET + 255) / 256;
    misc_k<<<NBc + 384 + 1, 256, 0, stream>>>(ei, W, batch, count, rank, wbt, gstart,
                                              NBc, E, N);
    gemm_att<<<(N + 63) / 64, 256, 0, stream>>>(x, wbt, att_src, att_dst,
                                                hc, ni, a_dst, N);
    int NB = (N + 255) / 256;
    scan_a<<<NB, 256, 0, stream>>>(count, offsets, bsums, N);
    scan_b<<<1, 256, 0, stream>>>(bsums, NB);
    scan_c<<<NB, 256, 0, stream>>>(offsets, bsums, N);
    scatter_k<<<(ET + 255) / 256, 256, 0, stream>>>(ei, rank, offsets, csr_src, E, N);
    aggregate_k<<<(N + 3) / 4, 256, 0, stream>>>((const unsigned*)hc, csr_src, offsets,
                                                 count, ni, a_dst, bias, outb, N);
    dim3 pg(NGRAPH, 8);
    pool_k<<<pg, 192, 0, stream>>>(outb, gstart, pooled);
    fc_k<<<NGRAPH, 64, 0, stream>>>(pooled, gstart, fc_w, fc_b, out);

    (void)n_in; (void)out_size; (void)ws_size;
}

// Round 4
// 298.219 us; speedup vs baseline: 1.1394x; 1.0485x over previous
//
#include <hip/hip_runtime.h>
#include <hip/hip_bf16.h>
#include <math.h>

#define HEADS 3
#define HO 384
#define NGRAPH 64
#define F_IN 256
#define SLOPE 0.2f

typedef __attribute__((ext_vector_type(8))) short bf8;
typedef __attribute__((ext_vector_type(4))) float f4;
typedef __attribute__((ext_vector_type(2))) unsigned u2v;
typedef __attribute__((ext_vector_type(4))) unsigned u4v;

// ---- bf16 helpers ----
__device__ __forceinline__ unsigned short bfr(float f) {
    unsigned u = __float_as_uint(f);
    u += 0x7fffu + ((u >> 16) & 1u);
    return (unsigned short)(u >> 16);
}
__device__ __forceinline__ float bflo(unsigned u) { return __uint_as_float(u << 16); }
__device__ __forceinline__ float bfhi(unsigned u) { return __uint_as_float(u & 0xffff0000u); }
__device__ __forceinline__ float lrelu(float v) { return (v > 0.f) ? v : SLOPE * v; }

// ---- biased-byte decode: bytes store q+128; v_perm builds half2(1024+b) (exact
// in f16), v_fma_mix_f32 accumulates wm*(1152+q) into f32 acc. The 1152*wsum
// offset is subtracted once in the epilogue. 12 insts per 8 channels. ----
__device__ __forceinline__ void mix2(float& a0, float& a1, unsigned h2, float wm) {
    asm("v_fma_mix_f32 %0, %2, %3, %0 op_sel:[0,0,0] op_sel_hi:[1,0,0]\n\t"
        "v_fma_mix_f32 %1, %2, %3, %1 op_sel:[1,0,0] op_sel_hi:[1,0,0]"
        : "+v"(a0), "+v"(a1)
        : "v"(h2), "v"(wm));
}
__device__ __forceinline__ void dec8_mix(float* acc, float wm, unsigned ux, unsigned uy,
                                         unsigned c64) {
    unsigned p0 = __builtin_amdgcn_perm(ux, c64, 0x00050004u); // [b0,0x64,b1,0x64]
    unsigned p1 = __builtin_amdgcn_perm(ux, c64, 0x00070006u);
    unsigned p2 = __builtin_amdgcn_perm(uy, c64, 0x00050004u);
    unsigned p3 = __builtin_amdgcn_perm(uy, c64, 0x00070006u);
    mix2(acc[0], acc[1], p0, wm);
    mix2(acc[2], acc[3], p1, wm);
    mix2(acc[4], acc[5], p2, wm);
    mix2(acc[6], acc[7], p3, wm);
}

// ---- K0: fused misc pre-pass (block-range dispatch) ----
__global__ __launch_bounds__(256) void misc_k(const int* __restrict__ ei,
                                              const float* __restrict__ W,
                                              const int* __restrict__ batch,
                                              int* __restrict__ count,
                                              int* __restrict__ rank,
                                              short* __restrict__ WbT,
                                              int* __restrict__ gstart,
                                              int NBc, int E, int N) {
    int b = blockIdx.x;
    if (b < NBc) {
        int e = b * 256 + threadIdx.x;
        int ET = E + N;
        if (e >= ET) return;
        int d = (e < E) ? ei[E + e] : (e - E);
        rank[e] = atomicAdd(&count[d], 1);   // unique within-dst rank
    } else if (b < NBc + 384) {
        int n = b - NBc;
        int k = threadIdx.x;
        WbT[n * 256 + k] = (short)bfr(W[(size_t)k * HO + n]);
    } else {
        int g = threadIdx.x;
        if (g > NGRAPH) return;
        int lo = 0, hi = N;
        while (lo < hi) { int mid = (lo + hi) >> 1; if (batch[mid] < g) lo = mid + 1; else hi = mid; }
        gstart[g] = lo;
    }
}

// ---- K1: LDS-staged bf16 MFMA GEMM + attention-dot + biased-int8 epilogue ----
// Outputs: Hc (N x 384 uchar, (q+128) per-(node,head) max-scaled), ni (N x 8 f32:
// [aSrc0,aSrc1,aSrc2,scale0][scale1,scale2,0,0]), aDstO (N x 3 f32).
#define XS_STRIDE 40
__global__ __launch_bounds__(256, 3) void gemm_att(const float* __restrict__ X,
                                                   const short* __restrict__ WbT,
                                                   const float* __restrict__ att_src,
                                                   const float* __restrict__ att_dst,
                                                   unsigned char* __restrict__ hc,
                                                   float* __restrict__ ni,
                                                   float* __restrict__ aDstO, int N) {
    __shared__ short Xs[64 * XS_STRIDE];
    __shared__ short Bs[384 * XS_STRIDE];
    __shared__ float lsS[64][8];
    __shared__ float lsD[64][8];
    __shared__ float lsM[64][8];
    __shared__ float sclS[64][4];
    int t = threadIdx.x;
    int w = t >> 6, lane = t & 63;
    int quad = lane >> 4, l15 = lane & 15;
    int rbase = blockIdx.x * 64;

    int sr = t >> 2;             // 0..63 (X row)
    int sko = (t & 3) * 8;       // 0,8,16,24
    int xrow = rbase + sr;
    xrow = (xrow < N) ? xrow : (N - 1);   // clamped rows never stored
    const float* xrp = X + (size_t)xrow * F_IN;

    f4 acc[4][6] = {};

    float4 p0 = *(const float4*)(xrp + sko);
    float4 p1 = *(const float4*)(xrp + sko + 4);

    for (int k0 = 0; k0 < F_IN; k0 += 32) {
        __syncthreads();
        {
            bf8 pk;
            pk[0] = (short)bfr(p0.x); pk[1] = (short)bfr(p0.y);
            pk[2] = (short)bfr(p0.z); pk[3] = (short)bfr(p0.w);
            pk[4] = (short)bfr(p1.x); pk[5] = (short)bfr(p1.y);
            pk[6] = (short)bfr(p1.z); pk[7] = (short)bfr(p1.w);
            *(bf8*)(&Xs[sr * XS_STRIDE + sko]) = pk;
        }
#pragma unroll
        for (int i = 0; i < 6; i++) {
            int n = i * 64 + sr;
            bf8 b = *(const bf8*)(WbT + (size_t)n * F_IN + k0 + sko);
            *(bf8*)(&Bs[n * XS_STRIDE + sko]) = b;
        }
        __syncthreads();
        if (k0 + 32 < F_IN) {    // prefetch next X chunk under the MFMAs
            p0 = *(const float4*)(xrp + k0 + 32 + sko);
            p1 = *(const float4*)(xrp + k0 + 32 + sko + 4);
        }
        bf8 ar[4], br[6];
#pragma unroll
        for (int at = 0; at < 4; at++)
            ar[at] = *(const bf8*)(&Xs[(at * 16 + l15) * XS_STRIDE + quad * 8]);
#pragma unroll
        for (int nt = 0; nt < 6; nt++)
            br[nt] = *(const bf8*)(&Bs[(w * 96 + nt * 16 + l15) * XS_STRIDE + quad * 8]);
#pragma unroll
        for (int at = 0; at < 4; at++)
#pragma unroll
            for (int nt = 0; nt < 6; nt++)
                acc[at][nt] = __builtin_amdgcn_mfma_f32_16x16x32_bf16(ar[at], br[nt], acc[at][nt], 0, 0, 0);
    }

    // ---- attention-dot epilogue ----
    // w=0: all head0 (split 6) | w=1: nt<2 head0, rest head1 (split 2)
    // w=2: nt<4 head1, rest head2 (split 4) | w=3: all head2 (split 0)
    const int splits[4] = {6, 2, 4, 0};
    int split = splits[w];
    float asv[6], adv[6];
#pragma unroll
    for (int nt = 0; nt < 6; nt++) {
        int c = w * 96 + nt * 16 + l15;
        asv[nt] = att_src[c];
        adv[nt] = att_dst[c];
    }
#pragma unroll
    for (int at = 0; at < 4; at++) {
#pragma unroll
        for (int r = 0; r < 4; r++) {
            float paS = 0.f, pbS = 0.f, paD = 0.f, pbD = 0.f;
#pragma unroll
            for (int nt = 0; nt < 6; nt++) {
                float v = acc[at][nt][r];
                if (nt < split) { paS += v * asv[nt]; paD += v * adv[nt]; }
                else            { pbS += v * asv[nt]; pbD += v * adv[nt]; }
            }
#pragma unroll
            for (int off = 1; off < 16; off <<= 1) {
                paS += __shfl_xor(paS, off); pbS += __shfl_xor(pbS, off);
                paD += __shfl_xor(paD, off); pbD += __shfl_xor(pbD, off);
            }
            if (l15 == 0) {
                int row = at * 16 + quad * 4 + r;
                lsS[row][w * 2 + 0] = paS; lsS[row][w * 2 + 1] = pbS;
                lsD[row][w * 2 + 0] = paD; lsD[row][w * 2 + 1] = pbD;
            }
        }
    }
    // ---- per-head abs-max (same split/reduce structure, fmax instead of +) ----
#pragma unroll
    for (int at = 0; at < 4; at++) {
#pragma unroll
        for (int r = 0; r < 4; r++) {
            float pa = 0.f, pb = 0.f;
#pragma unroll
            for (int nt = 0; nt < 6; nt++) {
                float v = fabsf(acc[at][nt][r]);
                if (nt < split) pa = fmaxf(pa, v); else pb = fmaxf(pb, v);
            }
#pragma unroll
            for (int off = 1; off < 16; off <<= 1) {
                pa = fmaxf(pa, __shfl_xor(pa, off));
                pb = fmaxf(pb, __shfl_xor(pb, off));
            }
            if (l15 == 0) {
                int row = at * 16 + quad * 4 + r;
                lsM[row][w * 2 + 0] = pa; lsM[row][w * 2 + 1] = pb;
            }
        }
    }
    __syncthreads();
    if (t < 64) {
        // per-head max over the two contributing waves (same combine as aSrc)
        float s0 = fmaxf(lsM[t][0], lsM[t][2]);
        float s1 = fmaxf(lsM[t][3], lsM[t][4]);
        float s2 = fmaxf(lsM[t][5], lsM[t][7]);
        sclS[t][0] = (s0 > 0.f) ? 127.f / s0 : 0.f;
        sclS[t][1] = (s1 > 0.f) ? 127.f / s1 : 0.f;
        sclS[t][2] = (s2 > 0.f) ? 127.f / s2 : 0.f;
        int node = rbase + t;
        if (node < N) {
            aDstO[node * 3 + 0] = lsD[t][0] + lsD[t][2];
            aDstO[node * 3 + 1] = lsD[t][3] + lsD[t][4];
            aDstO[node * 3 + 2] = lsD[t][5] + lsD[t][7];
            float4 nA, nB;
            nA.x = lsS[t][0] + lsS[t][2];
            nA.y = lsS[t][3] + lsS[t][4];
            nA.z = lsS[t][5] + lsS[t][7];
            nA.w = s0 / 127.f;            // pre-divided decode scale
            nB.x = s1 / 127.f;
            nB.y = s2 / 127.f;
            nB.z = 0.f; nB.w = 0.f;
            *(float4*)(ni + (size_t)node * 8) = nA;
            *(float4*)(ni + (size_t)node * 8 + 4) = nB;
        }
    }
    __syncthreads();
    // ---- biased int8 quantize + byte store: hc[node*384 + ch] = q+128 ----
#pragma unroll
    for (int at = 0; at < 4; at++) {
#pragma unroll
        for (int nt = 0; nt < 6; nt++) {
            int hd = (w * 96 + nt * 16) >> 7;   // head of this 16-ch tile
#pragma unroll
            for (int r = 0; r < 4; r++) {
                int row = at * 16 + quad * 4 + r;
                int node = rbase + row;
                float rq = sclS[row][hd];
                int qi = (int)rintf(acc[at][nt][r] * rq) + 128;
                if (node < N) hc[(size_t)node * 384 + w * 96 + nt * 16 + l15] = (unsigned char)qi;
            }
        }
    }
}

// ---- K2a/b/c: hierarchical exclusive scan ----
__global__ __launch_bounds__(256) void scan_a(const int* __restrict__ count,
                                              int* __restrict__ offsets,
                                              int* __restrict__ bsums, int N) {
    __shared__ int tmp[256];
    int t = threadIdx.x;
    int i = blockIdx.x * 256 + t;
    int v = (i < N) ? count[i] : 0;
    tmp[t] = v;
    __syncthreads();
    for (int off = 1; off < 256; off <<= 1) {
        int x = (t >= off) ? tmp[t - off] : 0;
        __syncthreads();
        tmp[t] += x;
        __syncthreads();
    }
    if (i < N) offsets[i] = tmp[t] - v;
    if (t == 255) bsums[blockIdx.x] = tmp[255];
}

__global__ __launch_bounds__(256) void scan_b(int* __restrict__ bsums, int NB) {
    __shared__ int tmp[256];
    int t = threadIdx.x;
    int v = (t < NB) ? bsums[t] : 0;
    tmp[t] = v;
    __syncthreads();
    for (int off = 1; off < 256; off <<= 1) {
        int x = (t >= off) ? tmp[t - off] : 0;
        __syncthreads();
        tmp[t] += x;
        __syncthreads();
    }
    if (t < NB) bsums[t] = tmp[t] - v;
}

__global__ __launch_bounds__(256) void scan_c(int* __restrict__ offsets,
                                              const int* __restrict__ bsums, int N) {
    int i = blockIdx.x * 256 + threadIdx.x;
    if (i < N) offsets[i] += bsums[blockIdx.x];
}

// ---- K3: scatter src index into CSR — plain write via precomputed rank ----
__global__ __launch_bounds__(256) void scatter_k(const int* __restrict__ ei,
                                                 const int* __restrict__ rank,
                                                 const int* __restrict__ offsets,
                                                 int* __restrict__ csr_src, int E, int N) {
    int e = blockIdx.x * 256 + threadIdx.x;
    int ET = E + N;
    if (e >= ET) return;
    int s, d;
    if (e < E) { s = ei[e]; d = ei[E + e]; } else { s = e - E; d = s; }
    csr_src[offsets[d] + rank[e]] = s;
}

// ---- K4: fused softmax + biased-int8 gather aggregation, one wave per dst ----
// Round-3 restructure (VALU-bound fix): weights/indices staged in LDS once per
// wave (4x ds_read_b128 per 8-edge batch replaces 32 bpermute + 16 cndmask),
// perm+fma_mix decode (12 insts/8ch vs 24). Offset 1152*wsum subtracted once.
__global__ __launch_bounds__(256) void aggregate_k(const unsigned* __restrict__ hcw,
                                                   const int* __restrict__ csr_src,
                                                   const int* __restrict__ offsets,
                                                   const int* __restrict__ count,
                                                   const float* __restrict__ ni,
                                                   const float* __restrict__ a_dst,
                                                   const float* __restrict__ bias,
                                                   unsigned* __restrict__ outb, int N) {
    __shared__ float ws[4][3][68];   // [wave][head][edge], 68-pad: heads hit distinct banks
    __shared__ int   si[4][64];      // [wave][edge] src index
    int wv = threadIdx.x >> 6;
    int wid = blockIdx.x * 4 + wv;
    int lane = threadIdx.x & 63;
    if (wid >= N) return;
    int start = offsets[wid], n = count[wid];
    float ad0 = a_dst[wid * 3 + 0], ad1 = a_dst[wid * 3 + 1], ad2 = a_dst[wid * 3 + 2];
    int hm = (lane < 48) ? (lane >> 4) : 0;   // head of this lane's 8 channels
    int off = (lane < 48) ? 2 * lane : 0;     // dword offset into 96-dword row
    float acc[8] = {0.f, 0.f, 0.f, 0.f, 0.f, 0.f, 0.f, 0.f};
    float wsum = 0.f;
    float i0, i1, i2;
    const unsigned c64 = 0x64646464u;

    if (n <= 64) {
        int sreg = 0;
        float l0 = -INFINITY, l1 = -INFINITY, l2 = -INFINITY;
        float s0v = 0.f, s1v = 0.f, s2v = 0.f;
        if (lane < n) {
            sreg = csr_src[start + lane];
            float4 A = *(const float4*)(ni + (size_t)sreg * 8);
            float4 B = *(const float4*)(ni + (size_t)sreg * 8 + 4);
            l0 = lrelu(A.x + ad0); l1 = lrelu(A.y + ad1); l2 = lrelu(A.z + ad2);
            s0v = A.w; s1v = B.x; s2v = B.y;
        }
        float m0 = l0, m1 = l1, m2 = l2;
#pragma unroll
        for (int o = 1; o < 64; o <<= 1) {
            m0 = fmaxf(m0, __shfl_xor(m0, o));
            m1 = fmaxf(m1, __shfl_xor(m1, o));
            m2 = fmaxf(m2, __shfl_xor(m2, o));
        }
        float e0 = (lane < n) ? expf(l0 - m0) : 0.f;
        float e1 = (lane < n) ? expf(l1 - m1) : 0.f;
        float e2 = (lane < n) ? expf(l2 - m2) : 0.f;
        float s0 = e0, s1 = e1, s2 = e2;
#pragma unroll
        for (int o = 1; o < 64; o <<= 1) {
            s0 += __shfl_xor(s0, o);
            s1 += __shfl_xor(s1, o);
            s2 += __shfl_xor(s2, o);
        }
        i0 = 1.f / (s0 + 1e-16f); i1 = 1.f / (s1 + 1e-16f); i2 = 1.f / (s2 + 1e-16f);
        // scale-folded unnormalized weights; 0 for idle lanes
        ws[wv][0][lane] = e0 * s0v;
        ws[wv][1][lane] = e1 * s1v;
        ws[wv][2][lane] = e2 * s2v;
        si[wv][lane] = sreg;
        __builtin_amdgcn_wave_barrier();   // order LDS writes before reads (in-wave)

        for (int j = 0; j < n; j += 8) {
            int4 ia = *(const int4*)&si[wv][j];        // broadcast reads
            int4 ib = *(const int4*)&si[wv][j + 4];
            u2v u0 = *(const u2v*)(hcw + (size_t)ia.x * 96 + off);
            u2v u1 = *(const u2v*)(hcw + (size_t)ia.y * 96 + off);
            u2v u2 = *(const u2v*)(hcw + (size_t)ia.z * 96 + off);
            u2v u3 = *(const u2v*)(hcw + (size_t)ia.w * 96 + off);
            u2v u4 = *(const u2v*)(hcw + (size_t)ib.x * 96 + off);
            u2v u5 = *(const u2v*)(hcw + (size_t)ib.y * 96 + off);
            u2v u6 = *(const u2v*)(hcw + (size_t)ib.z * 96 + off);
            u2v u7 = *(const u2v*)(hcw + (size_t)ib.w * 96 + off);
            float4 wa = *(const float4*)&ws[wv][hm][j];
            float4 wb = *(const float4*)&ws[wv][hm][j + 4];
            wsum += (wa.x + wa.y + wa.z + wa.w) + (wb.x + wb.y + wb.z + wb.w);
            dec8_mix(acc, wa.x, u0.x, u0.y, c64);
            dec8_mix(acc, wa.y, u1.x, u1.y, c64);
            dec8_mix(acc, wa.z, u2.x, u2.y, c64);
            dec8_mix(acc, wa.w, u3.x, u3.y, c64);
            dec8_mix(acc, wb.x, u4.x, u4.y, c64);
            dec8_mix(acc, wb.y, u5.x, u5.y, c64);
            dec8_mix(acc, wb.z, u6.x, u6.y, c64);
            dec8_mix(acc, wb.w, u7.x, u7.y, c64);
        }
    } else {
        float m0 = -INFINITY, m1 = -INFINITY, m2 = -INFINITY;
        for (int j = lane; j < n; j += 64) {
            int s = csr_src[start + j];
            float4 A = *(const float4*)(ni + (size_t)s * 8);
            m0 = fmaxf(m0, lrelu(A.x + ad0));
            m1 = fmaxf(m1, lrelu(A.y + ad1));
            m2 = fmaxf(m2, lrelu(A.z + ad2));
        }
#pragma unroll
        for (int o = 1; o < 64; o <<= 1) {
            m0 = fmaxf(m0, __shfl_xor(m0, o));
            m1 = fmaxf(m1, __shfl_xor(m1, o));
            m2 = fmaxf(m2, __shfl_xor(m2, o));
        }
        float s0 = 0.f, s1 = 0.f, s2 = 0.f;
        for (int j = lane; j < n; j += 64) {
            int s = csr_src[start + j];
            float4 A = *(const float4*)(ni + (size_t)s * 8);
            s0 += expf(lrelu(A.x + ad0) - m0);
            s1 += expf(lrelu(A.y + ad1) - m1);
            s2 += expf(lrelu(A.z + ad2) - m2);
        }
#pragma unroll
        for (int o = 1; o < 64; o <<= 1) {
            s0 += __shfl_xor(s0, o);
            s1 += __shfl_xor(s1, o);
            s2 += __shfl_xor(s2, o);
        }
        i0 = 1.f / (s0 + 1e-16f); i1 = 1.f / (s1 + 1e-16f); i2 = 1.f / (s2 + 1e-16f);
        for (int j = 0; j < n; j++) {
            int s = csr_src[start + j];
            float4 A = *(const float4*)(ni + (size_t)s * 8);
            float4 B = *(const float4*)(ni + (size_t)s * 8 + 4);
            float w0 = expf(lrelu(A.x + ad0) - m0) * A.w;
            float w1 = expf(lrelu(A.y + ad1) - m1) * B.x;
            float w2 = expf(lrelu(A.z + ad2) - m2) * B.y;
            float wm = (hm == 0) ? w0 : ((hm == 1) ? w1 : w2);
            u2v u = *(const u2v*)(hcw + (size_t)s * 96 + off);
            wsum += wm;
            dec8_mix(acc, wm, u.x, u.y, c64);
        }
    }

    if (lane < 48) {
        float im = (hm == 0) ? i0 : ((hm == 1) ? i1 : i2);
        float corr = 1152.f * wsum;          // remove (1024+128) bias per unit weight
        float4 b0 = *(const float4*)(bias + 8 * lane);
        float4 b1 = *(const float4*)(bias + 8 * lane + 4);
        float bb[8] = {b0.x, b0.y, b0.z, b0.w, b1.x, b1.y, b1.z, b1.w};
        u4v pk;
#pragma unroll
        for (int j = 0; j < 4; j++) {
            float x0 = (acc[2 * j] - corr) * im + bb[2 * j];
            float x1 = (acc[2 * j + 1] - corr) * im + bb[2 * j + 1];
            x0 = (x0 > 0.f) ? x0 : 0.f;
            x1 = (x1 > 0.f) ? x1 : 0.f;
            pk[j] = (unsigned)bfr(x0) | ((unsigned)bfr(x1) << 16);
        }
        *(u4v*)(outb + (size_t)wid * 192 + 4 * lane) = pk;
    }
}

// ---- K5: segment-sum pool over contiguous per-graph row ranges ----
__global__ __launch_bounds__(192) void pool_k(const unsigned* __restrict__ outb,
                                              const int* __restrict__ gstart,
                                              float* __restrict__ pooled) {
    int g = blockIdx.x;
    int chunk = blockIdx.y;
    int t = threadIdx.x;
    int lo = gstart[g], hi = gstart[g + 1];
    float al = 0.f, ah = 0.f;
    for (int r = lo + chunk; r < hi; r += 8) {
        unsigned u = outb[(size_t)r * 192 + t];
        al += bflo(u);
        ah += bfhi(u);
    }
    atomicAdd(&pooled[g * HO + 2 * t], al);
    atomicAdd(&pooled[g * HO + 2 * t + 1], ah);
}

// ---- K6: FC over pooled means ----
__global__ __launch_bounds__(64) void fc_k(const float* __restrict__ pooled,
                                           const int* __restrict__ gstart,
                                           const float* __restrict__ fc_w,
                                           const float* __restrict__ fc_b,
                                           float* __restrict__ out) {
    int g = blockIdx.x;
    int lane = threadIdx.x;
    float a0 = 0.f, a1 = 0.f;
#pragma unroll
    for (int k = 0; k < 6; k++) {
        int c = lane + 64 * k;
        float pv = pooled[g * HO + c];
        a0 += pv * fc_w[c * 2 + 0];
        a1 += pv * fc_w[c * 2 + 1];
    }
#pragma unroll
    for (int off = 32; off > 0; off >>= 1) {
        a0 += __shfl_down(a0, off);
        a1 += __shfl_down(a1, off);
    }
    if (lane == 0) {
        float cnt = fmaxf((float)(gstart[g + 1] - gstart[g]), 1.0f);
        out[g * 2 + 0] = a0 / cnt + fc_b[0];
        out[g * 2 + 1] = a1 / cnt + fc_b[1];
    }
}

extern "C" void kernel_launch(void* const* d_in, const int* in_sizes, int n_in,
                              void* d_out, int out_size, void* d_ws, size_t ws_size,
                              hipStream_t stream) {
    const float* x       = (const float*)d_in[0];
    const int*   ei      = (const int*)d_in[1];
    const int*   batch   = (const int*)d_in[2];
    const float* W       = (const float*)d_in[3];
    const float* att_src = (const float*)d_in[4];
    const float* att_dst = (const float*)d_in[5];
    const float* bias    = (const float*)d_in[6];
    const float* fc_w    = (const float*)d_in[7];
    const float* fc_b    = (const float*)d_in[8];
    float* out = (float*)d_out;

    const int N = in_sizes[2];
    const int E = in_sizes[1] / 2;
    const int ET = E + N;

    char* p = (char*)d_ws;
    auto alloc = [&](size_t bytes) -> char* {
        char* r = p;
        p += (bytes + 255) & ~(size_t)255;
        return r;
    };
    short*         wbt    = (short*)alloc((size_t)HO * F_IN * 2);
    unsigned char* hc     = (unsigned char*)alloc((size_t)N * 384);
    unsigned*      outb   = (unsigned*)alloc((size_t)N * 192 * 4);
    float*         ni     = (float*)alloc((size_t)N * 8 * 4);
    float*         a_dst  = (float*)alloc((size_t)N * 3 * 4);
    char*          zstart = p;
    int*           count  = (int*)alloc((size_t)N * 4);              // zeroed
    float*         pooled = (float*)alloc((size_t)NGRAPH * HO * 4);  // zeroed
    size_t         zbytes = (size_t)(p - zstart);
    int*           offsets = (int*)alloc((size_t)N * 4);
    int*           rank    = (int*)alloc((size_t)ET * 4);
    int*           bsums   = (int*)alloc(4096);
    int*           gstart  = (int*)alloc(1024);
    int*           csr_src = (int*)alloc((size_t)ET * 4);

    hipMemsetAsync(zstart, 0, zbytes, stream);

    int NBc = (ET + 255) / 256;
    misc_k<<<NBc + 384 + 1, 256, 0, stream>>>(ei, W, batch, count, rank, wbt, gstart,
                                              NBc, E, N);
    gemm_att<<<(N + 63) / 64, 256, 0, stream>>>(x, wbt, att_src, att_dst,
                                                hc, ni, a_dst, N);
    int NB = (N + 255) / 256;
    scan_a<<<NB, 256, 0, stream>>>(count, offsets, bsums, N);
    scan_b<<<1, 256, 0, stream>>>(bsums, NB);
    scan_c<<<NB, 256, 0, stream>>>(offsets, bsums, N);
    scatter_k<<<(ET + 255) / 256, 256, 0, stream>>>(ei, rank, offsets, csr_src, E, N);
    aggregate_k<<<(N + 3) / 4, 256, 0, stream>>>((const unsigned*)hc, csr_src, offsets,
                                                 count, ni, a_dst, bias, outb, N);
    dim3 pg(NGRAPH, 8);
    pool_k<<<pg, 192, 0, stream>>>(outb, gstart, pooled);
    fc_k<<<NGRAPH, 64, 0, stream>>>(pooled, gstart, fc_w, fc_b, out);

    (void)n_in; (void)out_size; (void)ws_size;
}